// Round 3
// baseline (661.063 us; speedup 1.0000x reference)
//
#include <hip/hip_runtime.h>
#include <hip/hip_bf16.h>
#include <math.h>

using short8 = __attribute__((ext_vector_type(8))) short;
using f32x4  = __attribute__((ext_vector_type(4))) float;

constexpr int B  = 1024;
constexpr int NN = 128;   // nodes per tree
constexpr int F  = 318;   // raw features

__device__ inline float bf2f(unsigned short u) {
    union { unsigned int i; float f; } x; x.i = ((unsigned int)u) << 16; return x.f;
}
__device__ inline unsigned short f2bf(float f) {
    union { float f; unsigned int i; } x; x.f = f;
    unsigned int r = x.i + 0x7fff + ((x.i >> 16) & 1);
    return (unsigned short)(r >> 16);
}

// ---------- trees [B][F][NN] f32 -> treesT [B][NN][320] bf16 (zero-pad c>=318) ----------
__global__ __launch_bounds__(256) void transpose_trees(const float* __restrict__ trees,
                                                       unsigned short* __restrict__ treesT)
{
    __shared__ float tile[32][129];
    const int b = blockIdx.x;
    const int c0 = blockIdx.y * 32;
#pragma unroll
    for (int i = 0; i < 16; ++i) {
        int e = threadIdx.x + i * 256;        // 32*128 = 4096
        int c = e >> 7, n = e & 127;
        float v = (c0 + c < F) ? trees[((size_t)b * F + c0 + c) * NN + n] : 0.f;
        tile[c][n] = v;
    }
    __syncthreads();
    const int n = threadIdx.x >> 1;
    const int ch = (threadIdx.x & 1) * 16;
    unsigned int out[8];
#pragma unroll
    for (int i = 0; i < 8; ++i) {
        float a = tile[ch + 2 * i][n];
        float bb = tile[ch + 2 * i + 1][n];
        out[i] = (unsigned int)f2bf(a) | ((unsigned int)f2bf(bb) << 16);
    }
    unsigned short* dst = treesT + ((size_t)b * NN + n) * 320 + c0 + ch;
    reinterpret_cast<uint4*>(dst)[0] = make_uint4(out[0], out[1], out[2], out[3]);
    reinterpret_cast<uint4*>(dst)[1] = make_uint4(out[4], out[5], out[6], out[7]);
}

// ---------- weight prepack into MFMA B-fragment order ----------
// packed element t = ((kb*(COUT/16)+ob)*64+lane)*8+j
// kb decomposition: S = kmul*(CC/32); ch = kb/S; rem = kb%S; k = rem/(CC/32); ks = rem%(CC/32)
// c = ch*CC + ks*32 + (lane>>4)*8 + j ; o = ob*16 + (lane&15)
__global__ __launch_bounds__(256) void prepack_w(const float* __restrict__ w,
                                                 unsigned short* __restrict__ wp,
                                                 int kmul, int OREAL, int CREAL,
                                                 int CC, int COUT, int KTOT)
{
    int t = blockIdx.x * 256 + threadIdx.x;
    if (t >= KTOT * COUT) return;
    int j = t & 7;
    int lane = (t >> 3) & 63;
    int rest = t >> 9;
    int obn = COUT / 16;
    int ob = rest % obn;
    int kb = rest / obn;
    int S = kmul * (CC / 32);
    int ch = kb / S;
    int rem = kb % S;
    int k = rem / (CC / 32);
    int ks = rem % (CC / 32);
    int c = ch * CC + ks * 32 + (lane >> 4) * 8 + j;
    int o = ob * 16 + (lane & 15);
    float v = 0.f;
    if (c < CREAL && o < OREAL)
        v = (kmul == 3) ? w[((size_t)o * CREAL + c) * 3 + k] : w[(size_t)o * CREAL + c];
    wp[t] = f2bf(v);
}

// ---------- unified GEMM: gather-on-stage, dbuf 2-phase pipeline, swizzled LDS ----------
// out[b][n][o] = bias[o] + sum_K A[n][K] * Wp[K][o]
// GATHER: staged G_k[n][c] = T(x[b][ idx[b][3n+k] ][c]);  T(v) = NORM ? max(v*inv - mu*inv, 0) : v
template <int CIN, int CC, int KM, int NF, int OREAL, int COUT, bool GATHER, bool NORM, bool STATS>
__global__ __launch_bounds__(256, 2) void gemm_tree(const unsigned short* __restrict__ xin, // [B][NN][CIN]
                                                    const int* __restrict__ idx,            // [B][3*NN]
                                                    const unsigned short* __restrict__ wp,
                                                    const float* __restrict__ bias,
                                                    const float* __restrict__ stats,
                                                    unsigned short* __restrict__ yout,      // [B][NN][COUT]
                                                    float* __restrict__ partials)
{
    constexpr int KSN   = CC / 32;            // kb per k-plane per chunk
    constexpr int NCH   = CIN / CC;           // chunks
    constexpr int GR    = CC / 8;             // 16B granules per row
    constexpr int PLANE = NN * CC * 2;        // bytes per k-plane
    constexpr int BUFB  = KM * PLANE;         // bytes per buffer
    constexpr int ITERS = (NN * KM * GR) / 256;
    constexpr int QN    = KM * KSN;           // kb per chunk
    constexpr int SMEM  = (2 * BUFB > 32768) ? 2 * BUFB : 32768;

    __shared__ __align__(16) char gbuf[SMEM];
    __shared__ float rbuf[8];

    const int b = blockIdx.x;
    const int tid = threadIdx.x;
    const int lane = tid & 63;
    const int wv = tid >> 6;
    const int wm = wv >> 1, wn = wv & 1;
    const int l15 = lane & 15, lh = lane >> 4;

    float inv = 1.f, nmi = 0.f;
    if (NORM) { float mu = stats[0]; inv = stats[1]; nmi = -mu * inv; }

    const unsigned short* xb = xin + (size_t)b * NN * CIN;

    // staging descriptors (fixed across chunks)
    unsigned int goff[ITERS], lby[ITERS];
#pragma unroll
    for (int i = 0; i < ITERS; ++i) {
        int it = i * 256 + tid;
        int g = it % GR;
        int n = (it / GR) % NN;
        int k = it / (GR * NN);
        int src = GATHER ? idx[b * 3 * NN + 3 * n + k] : n;
        goff[i] = (unsigned)(src * CIN + g * 8);
        lby[i]  = (unsigned)(k * PLANE + ((n * (CC * 2) + g * 16) ^ ((n & 7) << 4)));
    }

    f32x4 acc[4][NF];
#pragma unroll
    for (int mf = 0; mf < 4; ++mf)
#pragma unroll
        for (int nf = 0; nf < NF; ++nf) acc[mf][nf] = (f32x4)0.f;

    uint4 v[ITERS];
    auto stage_out = [&](char* wbase) {
#pragma unroll
        for (int i = 0; i < ITERS; ++i) {
            uint4 t = v[i];
            if (NORM) {
                unsigned int* pw = reinterpret_cast<unsigned int*>(&t);
#pragma unroll
                for (int q2 = 0; q2 < 4; ++q2) {
                    unsigned int u = pw[q2];
                    float f0 = __uint_as_float(u << 16);
                    float f1 = __uint_as_float(u & 0xffff0000u);
                    f0 = fmaxf(fmaf(f0, inv, nmi), 0.f);
                    f1 = fmaxf(fmaf(f1, inv, nmi), 0.f);
                    unsigned int r;
                    asm("v_cvt_pk_bf16_f32 %0, %1, %2" : "=v"(r) : "v"(f0), "v"(f1));
                    pw[q2] = r;
                }
            }
            *reinterpret_cast<uint4*>(wbase + lby[i]) = t;
        }
    };

    // prologue: stage chunk 0 into buf 0
#pragma unroll
    for (int i = 0; i < ITERS; ++i) v[i] = *reinterpret_cast<const uint4*>(xb + goff[i]);
    stage_out(gbuf);
    __syncthreads();

    int p = 0;
    for (int ch = 0; ch < NCH; ++ch) {
        if (ch + 1 < NCH) {
#pragma unroll
            for (int i = 0; i < ITERS; ++i)
                v[i] = *reinterpret_cast<const uint4*>(xb + (ch + 1) * CC + goff[i]);
        }
        const char* base = gbuf + p * BUFB;
#pragma unroll
        for (int q = 0; q < QN; ++q) {
            const int k = q / KSN, ks = q % KSN;
            const int kbg = ch * QN + q;
            short8 af[4];
#pragma unroll
            for (int mf = 0; mf < 4; ++mf) {
                int n = wm * 64 + mf * 16 + l15;
                af[mf] = *reinterpret_cast<const short8*>(
                    base + k * PLANE + ((n * (CC * 2) + ks * 64 + lh * 16) ^ ((n & 7) << 4)));
            }
#pragma unroll
            for (int nf = 0; nf < NF; ++nf) {
                const int ob = blockIdx.y * (2 * NF) + nf * 2 + wn;
                short8 bfr = *reinterpret_cast<const short8*>(
                    wp + (((size_t)kbg * (COUT / 16) + ob) * 64 + lane) * 8);
#pragma unroll
                for (int mf = 0; mf < 4; ++mf)
                    acc[mf][nf] = __builtin_amdgcn_mfma_f32_16x16x32_bf16(af[mf], bfr, acc[mf][nf], 0, 0, 0);
            }
        }
        if (ch + 1 < NCH) stage_out(gbuf + (p ^ 1) * BUFB);
        __syncthreads();
        p ^= 1;
    }

    // ---------------- epilogue: bias, stats, coalesced store via LDS tile ----------------
    unsigned short* xs = reinterpret_cast<unsigned short*>(gbuf);
    float bs[NF];
#pragma unroll
    for (int nf = 0; nf < NF; ++nf) {
        int o = blockIdx.y * (NF * 32) + nf * 32 + wn * 16 + l15;
        bs[nf] = (o < OREAL) ? bias[o] : 0.f;
    }
    float tsum = 0.f, tss = 0.f;
#pragma unroll
    for (int h = 0; h < NF / 4; ++h) {
        __syncthreads();
#pragma unroll
        for (int n4 = 0; n4 < 4; ++n4) {
            const int nf = h * 4 + n4;
#pragma unroll
            for (int mf = 0; mf < 4; ++mf) {
#pragma unroll
                for (int r = 0; r < 4; ++r) {
                    float val = acc[mf][nf][r] + bs[nf];
                    if (STATS) { tsum += val; tss += val * val; }
                    int row = wm * 64 + mf * 16 + lh * 4 + r;
                    int colL = n4 * 32 + wn * 16 + l15;
                    xs[row * 128 + colL] = f2bf(val);
                }
            }
        }
        __syncthreads();
#pragma unroll
        for (int i = 0; i < 8; ++i) {
            int e = tid + i * 256;            // 2048 x 16B
            int n = e >> 4, oL = (e & 15) * 8;
            *reinterpret_cast<uint4*>(yout + ((size_t)b * NN + n) * COUT + blockIdx.y * (NF * 32) + h * 128 + oL)
                = *reinterpret_cast<const uint4*>(xs + n * 128 + oL);
        }
    }

    if (STATS) {
#pragma unroll
        for (int s = 32; s; s >>= 1) { tsum += __shfl_down(tsum, s); tss += __shfl_down(tss, s); }
        if (lane == 0) { rbuf[wv * 2] = tsum; rbuf[wv * 2 + 1] = tss; }
        __syncthreads();
        if (tid == 0) {
            float s = rbuf[0] + rbuf[2] + rbuf[4] + rbuf[6];
            float q = rbuf[1] + rbuf[3] + rbuf[5] + rbuf[7];
            int gid = blockIdx.y * gridDim.x + blockIdx.x;
            partials[2 * gid] = s;
            partials[2 * gid + 1] = q;
        }
    }
}

// ---------- finalize global layernorm stats ----------
__global__ __launch_bounds__(256) void stats_kernel(const float* __restrict__ partials,
                                                    float* __restrict__ stats,
                                                    int npart, double ntot)
{
    __shared__ double sd[256], sd2[256];
    double s = 0.0, s2 = 0.0;
    for (int i = threadIdx.x; i < npart; i += 256) { s += (double)partials[2 * i]; s2 += (double)partials[2 * i + 1]; }
    sd[threadIdx.x] = s; sd2[threadIdx.x] = s2;
    __syncthreads();
    for (int k = 128; k > 0; k >>= 1) {
        if (threadIdx.x < k) { sd[threadIdx.x] += sd[threadIdx.x + k]; sd2[threadIdx.x] += sd2[threadIdx.x + k]; }
        __syncthreads();
    }
    if (threadIdx.x == 0) {
        double mu = sd[0] / ntot;
        double var = (sd2[0] - sd[0] * sd[0] / ntot) / (ntot - 1.0);
        double sdv = sqrt(var > 0.0 ? var : 0.0);
        stats[0] = (float)mu;
        stats[1] = (float)(1.0 / (sdv + 1e-5));
    }
}

// ---------- pooling + both heads ----------
__global__ __launch_bounds__(128) void pool_head_kernel(const unsigned short* __restrict__ y3, // [B][NN][128]
                                                        const float* __restrict__ stats,
                                                        const float* __restrict__ latw,
                                                        const float* __restrict__ latb,
                                                        const float* __restrict__ costw,
                                                        const float* __restrict__ costb,
                                                        float* __restrict__ out)
{
    const int b = blockIdx.x, t = threadIdx.x;
    const float mu = stats[0], inv = stats[1];
    const unsigned short* base = y3 + (size_t)b * NN * 128 + t;
    float m = -1e30f;
    for (int n = 0; n < NN; ++n) m = fmaxf(m, bf2f(base[n * 128]));
    const float pooled = fmaxf((m - mu) * inv, 0.f);
    __shared__ float pl[128];
    pl[t] = pooled;
    __syncthreads();
    const float* w = (t < 64) ? latw : costw;
    const int l = t & 63;
    float v = pl[l] * w[l] + pl[l + 64] * w[l + 64];
    for (int s = 32; s > 0; s >>= 1) v += __shfl_down(v, s);
    if (l == 0) {
        const float bb = (t < 64) ? latb[0] : costb[0];
        out[(t < 64 ? 0 : B) + b] = 1.f / (1.f + expf(-(v + bb)));
    }
}

// ---------- launch ----------
extern "C" void kernel_launch(void* const* d_in, const int* in_sizes, int n_in,
                              void* d_out, int out_size, void* d_ws, size_t ws_size,
                              hipStream_t stream)
{
    (void)in_sizes; (void)n_in; (void)out_size; (void)ws_size;
    const float* trees   = (const float*)d_in[0];
    const int*   indexes = (const int*)  d_in[1];
    const float* enc_w   = (const float*)d_in[2];
    const float* enc_b   = (const float*)d_in[3];
    const float* w1 = (const float*)d_in[4];
    const float* b1 = (const float*)d_in[5];
    const float* w2 = (const float*)d_in[6];
    const float* b2 = (const float*)d_in[7];
    const float* w3 = (const float*)d_in[8];
    const float* b3 = (const float*)d_in[9];
    const float* lat_w  = (const float*)d_in[10];
    const float* lat_b  = (const float*)d_in[11];
    const float* cost_w = (const float*)d_in[12];
    const float* cost_b = (const float*)d_in[13];
    float* out = (float*)d_out;

    char* ws = (char*)d_ws;
    size_t off = 0;
    auto alloc = [&](size_t bytes) -> char* {
        char* p = ws + off;
        off += (bytes + 255) & ~(size_t)255;
        return p;
    };
    unsigned short* wpe = (unsigned short*)alloc((size_t)320 * 128 * 2);
    unsigned short* wp1 = (unsigned short*)alloc((size_t)384 * 512 * 2);
    unsigned short* wp2 = (unsigned short*)alloc((size_t)1536 * 256 * 2);
    unsigned short* wp3 = (unsigned short*)alloc((size_t)768 * 128 * 2);
    unsigned short* x0  = (unsigned short*)alloc((size_t)B * NN * 128 * 2);
    unsigned short* y1  = (unsigned short*)alloc((size_t)B * NN * 512 * 2);
    // region R: treesT (83.9MB) aliases y2+y3 (100.6MB) — treesT dead after enc
    char* R = alloc((size_t)B * NN * (256 + 128) * 2);
    unsigned short* treesT = (unsigned short*)R;             // [B][NN][320]
    unsigned short* y2     = (unsigned short*)R;             // [B][NN][256]
    unsigned short* y3     = (unsigned short*)(R + (size_t)B * NN * 256 * 2);
    float* partials = (float*)alloc((size_t)4096 * 2 * 4);
    float* stats    = (float*)alloc(8 * 4);

    transpose_trees<<<dim3(B, 10), dim3(256), 0, stream>>>(trees, treesT);

    prepack_w<<<dim3((320 * 128 + 255) / 256),  dim3(256), 0, stream>>>(enc_w, wpe, 1, 109, 318, 64, 128, 320);
    prepack_w<<<dim3((384 * 512 + 255) / 256),  dim3(256), 0, stream>>>(w1, wp1, 3, 512, 109, 32, 512, 384);
    prepack_w<<<dim3((1536 * 256 + 255) / 256), dim3(256), 0, stream>>>(w2, wp2, 3, 256, 512, 32, 256, 1536);
    prepack_w<<<dim3((768 * 128 + 255) / 256),  dim3(256), 0, stream>>>(w3, wp3, 3, 128, 256, 32, 128, 768);

    // encoder: [B][NN][320] @ [320][128] -> x0 [B][NN][128]
    gemm_tree<320, 64, 1, 4, 109, 128, false, false, false>
        <<<dim3(B, 1), dim3(256), 0, stream>>>(treesT, indexes, wpe, enc_b, stats, x0, partials);

    // conv1: gather(x0) [B][NN][384K] @ [384][512] -> y1 (o-split in 2)
    gemm_tree<128, 32, 3, 8, 512, 512, true, false, true>
        <<<dim3(B, 2), dim3(256), 0, stream>>>(x0, indexes, wp1, b1, stats, y1, partials);
    stats_kernel<<<dim3(1), dim3(256), 0, stream>>>(partials, stats + 0, 2048, (double)((size_t)B * 512 * NN));

    // conv2: gather(norm(y1)) [B][NN][1536K] @ [1536][256] -> y2
    gemm_tree<512, 32, 3, 8, 256, 256, true, true, true>
        <<<dim3(B, 1), dim3(256), 0, stream>>>(y1, indexes, wp2, b2, stats + 0, y2, partials);
    stats_kernel<<<dim3(1), dim3(256), 0, stream>>>(partials, stats + 2, 1024, (double)((size_t)B * 256 * NN));

    // conv3: gather(norm(y2)) [B][NN][768K] @ [768][128] -> y3
    gemm_tree<256, 32, 3, 4, 128, 128, true, true, true>
        <<<dim3(B, 1), dim3(256), 0, stream>>>(y2, indexes, wp3, b3, stats + 2, y3, partials);
    stats_kernel<<<dim3(1), dim3(256), 0, stream>>>(partials, stats + 4, 1024, (double)((size_t)B * 128 * NN));

    pool_head_kernel<<<dim3(B), dim3(128), 0, stream>>>(y3, stats + 4, lat_w, lat_b, cost_w, cost_b, out);
}

// Round 4
// 478.908 us; speedup vs baseline: 1.3804x; 1.3804x over previous
//
#include <hip/hip_runtime.h>
#include <hip/hip_bf16.h>
#include <math.h>

using short8 = __attribute__((ext_vector_type(8))) short;
using f32x16 = __attribute__((ext_vector_type(16))) float;

constexpr int B  = 1024;
constexpr int NN = 128;   // nodes per tree
constexpr int F  = 318;   // raw features

__device__ inline float bf2f(unsigned short u) {
    union { unsigned int i; float f; } x; x.i = ((unsigned int)u) << 16; return x.f;
}
__device__ inline unsigned short f2bf(float f) {
    union { float f; unsigned int i; } x; x.f = f;
    unsigned int r = x.i + 0x7fff + ((x.i >> 16) & 1);
    return (unsigned short)(r >> 16);
}

// ---------- trees [B][F][NN] f32 -> treesT [B][NN][320] bf16 (zero-pad c>=318) ----------
__global__ __launch_bounds__(256) void transpose_trees(const float* __restrict__ trees,
                                                       unsigned short* __restrict__ treesT)
{
    __shared__ float tile[32][129];
    const int b = blockIdx.x;
    const int c0 = blockIdx.y * 32;
#pragma unroll
    for (int i = 0; i < 16; ++i) {
        int e = threadIdx.x + i * 256;        // 32*128 = 4096
        int c = e >> 7, n = e & 127;
        float v = (c0 + c < F) ? trees[((size_t)b * F + c0 + c) * NN + n] : 0.f;
        tile[c][n] = v;
    }
    __syncthreads();
    const int n = threadIdx.x >> 1;
    const int ch = (threadIdx.x & 1) * 16;
    unsigned int out[8];
#pragma unroll
    for (int i = 0; i < 8; ++i) {
        float a = tile[ch + 2 * i][n];
        float bb = tile[ch + 2 * i + 1][n];
        out[i] = (unsigned int)f2bf(a) | ((unsigned int)f2bf(bb) << 16);
    }
    unsigned short* dst = treesT + ((size_t)b * NN + n) * 320 + c0 + ch;
    reinterpret_cast<uint4*>(dst)[0] = make_uint4(out[0], out[1], out[2], out[3]);
    reinterpret_cast<uint4*>(dst)[1] = make_uint4(out[4], out[5], out[6], out[7]);
}

// ---------- weight prepack into 32x32x16 MFMA B-fragment order ----------
// element t = ((kbg*(COUT/32)+ob)*64+lane)*8+j
// kbg = (k*NCC + cc)*KS + ks ; c = cc*CC + ks*16 + (lane>>5)*8 + j ; o = ob*32 + (lane&31)
__global__ __launch_bounds__(256) void prepack_w32(const float* __restrict__ w,
                                                   unsigned short* __restrict__ wp,
                                                   int kmul, int OREAL, int CREAL,
                                                   int CC, int COUT, int KS, int NCC, int KTOT)
{
    int t = blockIdx.x * 256 + threadIdx.x;
    if (t >= KTOT * COUT) return;
    int j = t & 7;
    int lane = (t >> 3) & 63;
    int rest = t >> 9;
    int obn = COUT / 32;
    int ob = rest % obn;
    int kbg = rest / obn;
    int ks = kbg % KS;
    int t2 = kbg / KS;
    int cc = t2 % NCC;
    int k  = t2 / NCC;
    int c = cc * CC + ks * 16 + (lane >> 5) * 8 + j;
    int o = ob * 32 + (lane & 31);
    float v = 0.f;
    if (c < CREAL && o < OREAL)
        v = (kmul == 3) ? w[((size_t)o * CREAL + c) * 3 + k] : w[(size_t)o * CREAL + c];
    wp[t] = f2bf(v);
}

// ---------- unified GEMM: LDS-side gather, 32x32x16 MFMA, dbuf 2-phase, 1 barrier/chunk ----------
// out[b][n][o] = bias[o] + sum_K A[n][K] * Wp[K][o]
// A row for K-plane k = T(x[b][ idx[b][3n+k] ][c]) (gather resolved at LDS A-frag read)
// T(v) = NORM ? max(v*inv - mu*inv, 0) : v   (applied at stage time)
template <int CIN, int CC, int NPL, int OREAL, int COUT, bool GATHER, bool NORM, bool STATS>
__global__ __launch_bounds__(256, 2) void gemm_tree(const unsigned short* __restrict__ xin, // [B][NN][CIN]
                                                    const int* __restrict__ idx,            // [B][3*NN]
                                                    const unsigned short* __restrict__ wp,
                                                    const float* __restrict__ bias,
                                                    const float* __restrict__ stats,
                                                    unsigned short* __restrict__ yout,      // [B][NN][COUT]
                                                    float* __restrict__ partials)
{
    constexpr int NCC    = CIN / CC;
    constexpr int NCHUNK = NPL * NCC;
    constexpr int KS     = CC / 16;           // K-steps per chunk
    constexpr int GR     = CC / 8;            // 16B granules per row
    constexpr int NSH    = (GR == 16) ? 4 : 3;
    constexpr int ITERS  = (NN * GR) / 256;   // granules staged per thread per chunk
    constexpr int BUFB   = NN * CC * 2;       // bytes per buffer
    constexpr int SMEM   = (2 * BUFB > 32768) ? 2 * BUFB : 32768;
    constexpr int SPL    = GATHER ? NPL : 1;

    __shared__ __align__(16) char gbuf[SMEM];

    const int b = blockIdx.x;
    const int tid = threadIdx.x;
    const int lane = tid & 63;
    const int wv = tid >> 6;
    const int wm = wv >> 1, wn = wv & 1;
    const int l31 = lane & 31, lh2 = lane >> 5;

    float inv = 1.f, nmi = 0.f;
    if (NORM) { float mu = stats[0]; inv = stats[1]; nmi = -mu * inv; }

    const unsigned short* xb = xin + (size_t)b * NN * CIN;

    // per-thread staging descriptors
    const int g = tid & (GR - 1);
    const int coli = g * 8;                    // element offset within chunk row
    int nrow[ITERS];
    unsigned lby[ITERS];
#pragma unroll
    for (int i = 0; i < ITERS; ++i) {
        int n = (i * 256 + tid) >> NSH;
        nrow[i] = n;
        lby[i] = (unsigned)(n * (CC * 2) + ((g ^ (n & 7)) << 4));
    }
    int srcs[SPL][ITERS];
#pragma unroll
    for (int k = 0; k < SPL; ++k)
#pragma unroll
        for (int i = 0; i < ITERS; ++i)
            srcs[k][i] = GATHER ? idx[b * 3 * NN + 3 * nrow[i] + k] : nrow[i];

    f32x16 acc[2][2];
#pragma unroll
    for (int rf = 0; rf < 2; ++rf)
#pragma unroll
        for (int cf = 0; cf < 2; ++cf) acc[rf][cf] = (f32x16)0.f;

    uint4 v[ITERS];
    auto stor = [&](char* wb) {
#pragma unroll
        for (int i = 0; i < ITERS; ++i) {
            uint4 t = v[i];
            if (NORM) {
                unsigned int* pw = reinterpret_cast<unsigned int*>(&t);
#pragma unroll
                for (int q = 0; q < 4; ++q) {
                    unsigned int u = pw[q];
                    float f0 = __uint_as_float(u << 16);
                    float f1 = __uint_as_float(u & 0xffff0000u);
                    f0 = fmaxf(fmaf(f0, inv, nmi), 0.f);
                    f1 = fmaxf(fmaf(f1, inv, nmi), 0.f);
                    unsigned int r;
                    asm("v_cvt_pk_bf16_f32 %0, %1, %2" : "=v"(r) : "v"(f0), "v"(f1));
                    pw[q] = r;
                }
            }
            *reinterpret_cast<uint4*>(wb + lby[i]) = t;
        }
    };

    // A-frag read bases (rows are wave-deterministic; gather already resolved in staging idx)
    const unsigned ab0 = (unsigned)((wm * 64 + l31) * (CC * 2));
    const unsigned ab1 = (unsigned)((wm * 64 + 32 + l31) * (CC * 2));
    const int ax = l31 & 7;
    const int ob0 = blockIdx.y * 4 + wn * 2;

    // prologue: stage chunk 0 (k=0, cc=0) into buf 0
#pragma unroll
    for (int i = 0; i < ITERS; ++i)
        v[i] = *reinterpret_cast<const uint4*>(xb + (size_t)srcs[0][i] * CIN + coli);
    stor(gbuf);
    __syncthreads();

    int p = 0;
#pragma unroll
    for (int k = 0; k < NPL; ++k) {
#pragma unroll
        for (int cc = 0; cc < NCC; ++cc) {
            const int ci = k * NCC + cc;
            if (ci + 1 < NCHUNK) {
                const int k2  = (cc + 1 < NCC) ? k : ((k + 1 < NPL) ? k + 1 : 0);
                const int cc2 = (cc + 1 < NCC) ? cc + 1 : 0;
#pragma unroll
                for (int i = 0; i < ITERS; ++i)
                    v[i] = *reinterpret_cast<const uint4*>(
                        xb + (size_t)srcs[GATHER ? k2 : 0][i] * CIN + cc2 * CC + coli);
            }
            const char* base = gbuf + p * BUFB;
#pragma unroll
            for (int ks = 0; ks < KS; ++ks) {
                const int kbg = ci * KS + ks;
                const unsigned co = (unsigned)(((ks * 2 + lh2) ^ ax) << 4);
                short8 a0 = *reinterpret_cast<const short8*>(base + ab0 + co);
                short8 a1 = *reinterpret_cast<const short8*>(base + ab1 + co);
                short8 b0 = *reinterpret_cast<const short8*>(
                    wp + ((size_t)(kbg * (COUT / 32) + ob0) * 64 + lane) * 8);
                short8 b1 = *reinterpret_cast<const short8*>(
                    wp + ((size_t)(kbg * (COUT / 32) + ob0 + 1) * 64 + lane) * 8);
                acc[0][0] = __builtin_amdgcn_mfma_f32_32x32x16_bf16(a0, b0, acc[0][0], 0, 0, 0);
                acc[0][1] = __builtin_amdgcn_mfma_f32_32x32x16_bf16(a0, b1, acc[0][1], 0, 0, 0);
                acc[1][0] = __builtin_amdgcn_mfma_f32_32x32x16_bf16(a1, b0, acc[1][0], 0, 0, 0);
                acc[1][1] = __builtin_amdgcn_mfma_f32_32x32x16_bf16(a1, b1, acc[1][1], 0, 0, 0);
            }
            if (ci + 1 < NCHUNK) stor(gbuf + (p ^ 1) * BUFB);
            __syncthreads();
            p ^= 1;
        }
    }

    // ---------------- epilogue: bias, stats, coalesced store via LDS tile ----------------
    unsigned short* xs = reinterpret_cast<unsigned short*>(gbuf);
    float* rbuf = reinterpret_cast<float*>(gbuf + 49152);   // only touched when STATS (SMEM=64KB then)
    float bs[2];
#pragma unroll
    for (int cf = 0; cf < 2; ++cf) {
        int o = blockIdx.y * 128 + wn * 64 + cf * 32 + l31;
        bs[cf] = (o < OREAL) ? bias[o] : 0.f;
    }
    float tsum = 0.f, tss = 0.f;
#pragma unroll
    for (int rf = 0; rf < 2; ++rf)
#pragma unroll
        for (int cf = 0; cf < 2; ++cf)
#pragma unroll
            for (int r = 0; r < 16; ++r) {
                float val = acc[rf][cf][r] + bs[cf];
                if (STATS) { tsum += val; tss += val * val; }
                int row = wm * 64 + rf * 32 + (r & 3) + 8 * (r >> 2) + 4 * lh2;
                int col = wn * 64 + cf * 32 + l31;
                xs[row * 128 + col] = f2bf(val);
            }
    __syncthreads();
#pragma unroll
    for (int i = 0; i < 8; ++i) {
        int e = tid + i * 256;            // 2048 x 16B
        int n = e >> 4, oL = (e & 15) * 8;
        *reinterpret_cast<uint4*>(yout + ((size_t)b * NN + n) * COUT + blockIdx.y * 128 + oL)
            = *reinterpret_cast<const uint4*>(xs + n * 128 + oL);
    }

    if (STATS) {
#pragma unroll
        for (int s = 32; s; s >>= 1) { tsum += __shfl_down(tsum, s); tss += __shfl_down(tss, s); }
        if (lane == 0) { rbuf[wv * 2] = tsum; rbuf[wv * 2 + 1] = tss; }
        __syncthreads();
        if (tid == 0) {
            float s = rbuf[0] + rbuf[2] + rbuf[4] + rbuf[6];
            float q = rbuf[1] + rbuf[3] + rbuf[5] + rbuf[7];
            int gid = blockIdx.y * gridDim.x + blockIdx.x;
            partials[2 * gid] = s;
            partials[2 * gid + 1] = q;
        }
    }
}

// ---------- finalize global layernorm stats ----------
__global__ __launch_bounds__(256) void stats_kernel(const float* __restrict__ partials,
                                                    float* __restrict__ stats,
                                                    int npart, double ntot)
{
    __shared__ double sd[256], sd2[256];
    double s = 0.0, s2 = 0.0;
    for (int i = threadIdx.x; i < npart; i += 256) { s += (double)partials[2 * i]; s2 += (double)partials[2 * i + 1]; }
    sd[threadIdx.x] = s; sd2[threadIdx.x] = s2;
    __syncthreads();
    for (int k = 128; k > 0; k >>= 1) {
        if (threadIdx.x < k) { sd[threadIdx.x] += sd[threadIdx.x + k]; sd2[threadIdx.x] += sd2[threadIdx.x + k]; }
        __syncthreads();
    }
    if (threadIdx.x == 0) {
        double mu = sd[0] / ntot;
        double var = (sd2[0] - sd[0] * sd[0] / ntot) / (ntot - 1.0);
        double sdv = sqrt(var > 0.0 ? var : 0.0);
        stats[0] = (float)mu;
        stats[1] = (float)(1.0 / (sdv + 1e-5));
    }
}

// ---------- pooling + both heads ----------
__global__ __launch_bounds__(128) void pool_head_kernel(const unsigned short* __restrict__ y3, // [B][NN][128]
                                                        const float* __restrict__ stats,
                                                        const float* __restrict__ latw,
                                                        const float* __restrict__ latb,
                                                        const float* __restrict__ costw,
                                                        const float* __restrict__ costb,
                                                        float* __restrict__ out)
{
    const int b = blockIdx.x, t = threadIdx.x;
    const float mu = stats[0], inv = stats[1];
    const unsigned short* base = y3 + (size_t)b * NN * 128 + t;
    float m = -1e30f;
    for (int n = 0; n < NN; ++n) m = fmaxf(m, bf2f(base[n * 128]));
    const float pooled = fmaxf((m - mu) * inv, 0.f);
    __shared__ float pl[128];
    pl[t] = pooled;
    __syncthreads();
    const float* w = (t < 64) ? latw : costw;
    const int l = t & 63;
    float v = pl[l] * w[l] + pl[l + 64] * w[l + 64];
    for (int s = 32; s > 0; s >>= 1) v += __shfl_down(v, s);
    if (l == 0) {
        const float bb = (t < 64) ? latb[0] : costb[0];
        out[(t < 64 ? 0 : B) + b] = 1.f / (1.f + expf(-(v + bb)));
    }
}

// ---------- launch ----------
extern "C" void kernel_launch(void* const* d_in, const int* in_sizes, int n_in,
                              void* d_out, int out_size, void* d_ws, size_t ws_size,
                              hipStream_t stream)
{
    (void)in_sizes; (void)n_in; (void)out_size; (void)ws_size;
    const float* trees   = (const float*)d_in[0];
    const int*   indexes = (const int*)  d_in[1];
    const float* enc_w   = (const float*)d_in[2];
    const float* enc_b   = (const float*)d_in[3];
    const float* w1 = (const float*)d_in[4];
    const float* b1 = (const float*)d_in[5];
    const float* w2 = (const float*)d_in[6];
    const float* b2 = (const float*)d_in[7];
    const float* w3 = (const float*)d_in[8];
    const float* b3 = (const float*)d_in[9];
    const float* lat_w  = (const float*)d_in[10];
    const float* lat_b  = (const float*)d_in[11];
    const float* cost_w = (const float*)d_in[12];
    const float* cost_b = (const float*)d_in[13];
    float* out = (float*)d_out;

    char* ws = (char*)d_ws;
    size_t off = 0;
    auto alloc = [&](size_t bytes) -> char* {
        char* p = ws + off;
        off += (bytes + 255) & ~(size_t)255;
        return p;
    };
    unsigned short* wpe = (unsigned short*)alloc((size_t)320 * 128 * 2);
    unsigned short* wp1 = (unsigned short*)alloc((size_t)384 * 512 * 2);
    unsigned short* wp2 = (unsigned short*)alloc((size_t)1536 * 256 * 2);
    unsigned short* wp3 = (unsigned short*)alloc((size_t)768 * 128 * 2);
    unsigned short* x0  = (unsigned short*)alloc((size_t)B * NN * 128 * 2);
    unsigned short* y1  = (unsigned short*)alloc((size_t)B * NN * 512 * 2);
    // region R: treesT (83.9MB) aliases y2+y3 (100.6MB) — treesT dead after enc
    char* R = alloc((size_t)B * NN * (256 + 128) * 2);
    unsigned short* treesT = (unsigned short*)R;             // [B][NN][320]
    unsigned short* y2     = (unsigned short*)R;             // [B][NN][256]
    unsigned short* y3     = (unsigned short*)(R + (size_t)B * NN * 256 * 2);
    float* partials = (float*)alloc((size_t)4096 * 2 * 4);
    float* stats    = (float*)alloc(8 * 4);

    transpose_trees<<<dim3(B, 10), dim3(256), 0, stream>>>(trees, treesT);

    prepack_w32<<<dim3((320 * 128 + 255) / 256),  dim3(256), 0, stream>>>(enc_w, wpe, 1, 109, 318, 64, 128, 4, 5, 320);
    prepack_w32<<<dim3((384 * 512 + 255) / 256),  dim3(256), 0, stream>>>(w1, wp1, 3, 512, 109, 128, 512, 8, 1, 384);
    prepack_w32<<<dim3((1536 * 256 + 255) / 256), dim3(256), 0, stream>>>(w2, wp2, 3, 256, 512, 128, 256, 8, 4, 1536);
    prepack_w32<<<dim3((768 * 128 + 255) / 256),  dim3(256), 0, stream>>>(w3, wp3, 3, 128, 256, 128, 128, 8, 2, 768);

    // encoder: [B][NN][320] @ [320][128] -> x0 [B][NN][128]
    gemm_tree<320, 64, 1, 109, 128, false, false, false>
        <<<dim3(B, 1), dim3(256), 0, stream>>>(treesT, indexes, wpe, enc_b, stats, x0, partials);

    // conv1: gather(x0) [B][NN][384K] @ [384][512] -> y1 (4 o-tiles of 128)
    gemm_tree<128, 128, 3, 512, 512, true, false, true>
        <<<dim3(B, 4), dim3(256), 0, stream>>>(x0, indexes, wp1, b1, stats, y1, partials);
    stats_kernel<<<dim3(1), dim3(256), 0, stream>>>(partials, stats + 0, 4096, (double)((size_t)B * 512 * NN));

    // conv2: gather(norm(y1)) [B][NN][1536K] @ [1536][256] -> y2 (2 o-tiles)
    gemm_tree<512, 128, 3, 256, 256, true, true, true>
        <<<dim3(B, 2), dim3(256), 0, stream>>>(y1, indexes, wp2, b2, stats + 0, y2, partials);
    stats_kernel<<<dim3(1), dim3(256), 0, stream>>>(partials, stats + 2, 2048, (double)((size_t)B * 256 * NN));

    // conv3: gather(norm(y2)) [B][NN][768K] @ [768][128] -> y3
    gemm_tree<256, 128, 3, 128, 128, true, true, true>
        <<<dim3(B, 1), dim3(256), 0, stream>>>(y2, indexes, wp3, b3, stats + 2, y3, partials);
    stats_kernel<<<dim3(1), dim3(256), 0, stream>>>(partials, stats + 4, 1024, (double)((size_t)B * 128 * NN));

    pool_head_kernel<<<dim3(B), dim3(128), 0, stream>>>(y3, stats + 4, lat_w, lat_b, cost_w, cost_b, out);
}